// Round 14
// baseline (1327.654 us; speedup 1.0000x reference)
//
#include <hip/hip_runtime.h>
#include <hip/hip_fp16.h>

#define HD 128

typedef __attribute__((ext_vector_type(8))) _Float16 f16x8;
typedef __attribute__((ext_vector_type(4))) float f32x4;
typedef unsigned int u32;
typedef unsigned long long u64;

struct h4s { __half2 a, b; };  // 4 fp16 = 8 B

__device__ __forceinline__ float lrelu(float x, float s) { return x > 0.f ? x : s * x; }

__device__ __forceinline__ float2 u32f2(u32 v) {
  __half2 h;
  *reinterpret_cast<u32*>(&h) = v;
  return __half22float2(h);
}
__device__ __forceinline__ u32 f2u32(float2 f) {
  __half2 h = __float22half2_rn(f);
  return *reinterpret_cast<u32*>(&h);
}

// BN scale/shift from raw stats: st[f]=sum, st[HD+f]=sumsq
__device__ __forceinline__ float2 bn_coeff(const float* st, const float* g,
                                           const float* be, float invn, int f) {
  float m = st[f] * invn;
  float v = st[HD + f] * invn - m * m;
  float sc = g[f] * rsqrtf(v + 1e-5f);
  return make_float2(sc, be[f] - m * sc);
}

// ---------------- graph prep ----------------
__global__ void k_edge_count(const int* __restrict__ src, const int* __restrict__ dst,
                             int* __restrict__ degc, int* __restrict__ cnt,
                             int* __restrict__ ledge, int E) {
  int e = blockIdx.x * blockDim.x + threadIdx.x;
  if (e < E) {
    atomicAdd(&degc[src[e]], 1);
    ledge[e] = atomicAdd(&cnt[dst[e]], 1);
  }
}

__global__ __launch_bounds__(1024) void k_scan1(const int* __restrict__ cnt,
                                                int* __restrict__ rowptr,
                                                int* __restrict__ bsums,
                                                float* __restrict__ stats, int n) {
  if (blockIdx.x == 0 && threadIdx.x < 6 * HD) stats[threadIdx.x] = 0.f;
  __shared__ int buf[1024];
  int i = blockIdx.x * 1024 + threadIdx.x;
  int v = (i < n) ? cnt[i] : 0;
  buf[threadIdx.x] = v;
  __syncthreads();
  for (int o = 1; o < 1024; o <<= 1) {
    int t = (threadIdx.x >= (unsigned)o) ? buf[threadIdx.x - o] : 0;
    __syncthreads();
    buf[threadIdx.x] += t;
    __syncthreads();
  }
  if (i < n) rowptr[i] = buf[threadIdx.x] - v;
  if (threadIdx.x == 1023) bsums[blockIdx.x] = buf[1023];
}

__global__ __launch_bounds__(1024) void k_scan3(int* __restrict__ rowptr,
                                                const int* __restrict__ bsums,
                                                const int* __restrict__ degc,
                                                float* __restrict__ dinv, int n, int Etot,
                                                int nb) {
  __shared__ int blockoff;
  if (nb <= 64) {
    if (threadIdx.x < 64) {
      int lane = threadIdx.x;
      int v = (lane < nb) ? bsums[lane] : 0;
      int inc = v;
#pragma unroll
      for (int o = 1; o < 64; o <<= 1) {
        int t = __shfl_up(inc, o, 64);
        if (lane >= o) inc += t;
      }
      if (lane == (int)blockIdx.x) blockoff = inc - v;
    }
  } else if (threadIdx.x == 0) {
    int sum = 0;
    for (int t = 0; t < (int)blockIdx.x; ++t) sum += bsums[t];
    blockoff = sum;
  }
  __syncthreads();
  int i = blockIdx.x * 1024 + threadIdx.x;
  if (i < n) {
    rowptr[i] += blockoff;
    int dg = degc[i];
    dinv[i] = dg > 0 ? rsqrtf((float)dg) : 0.f;
  }
  if (i == 0) rowptr[n] = Etot;
}

// atomic-free CSR fill
__global__ void k_fill(const int* __restrict__ src, const int* __restrict__ dst,
                       const int* __restrict__ ledge, const int* __restrict__ rowptr,
                       const float* __restrict__ dinv, uint2* __restrict__ cw, int E) {
  int e = blockIdx.x * blockDim.x + threadIdx.x;
  if (e < E) {
    int s = src[e], d = dst[e];
    int p = rowptr[d] + ledge[e];
    cw[p] = make_uint2((u32)s, __float_as_uint(-dinv[s] * dinv[d]));
  }
}

// ---------------- props ----------------
__global__ void k_prop3(const int* __restrict__ rowptr, const uint2* __restrict__ cw,
                        const float* __restrict__ Hs, const float* __restrict__ Sub,
                        float* __restrict__ Out, float scale, int n) {
  int r = blockIdx.x * blockDim.x + threadIdx.x;
  if (r >= n) return;
  int b = rowptr[r], e = rowptr[r + 1];
  float a0 = 0.f, a1 = 0.f, a2 = 0.f;
  for (int j = b; j < e; ++j) {
    uint2 m = cw[j];
    int s = (int)m.x;
    float w = __uint_as_float(m.y);
    a0 = fmaf(w, Hs[s * 3 + 0], a0);
    a1 = fmaf(w, Hs[s * 3 + 1], a1);
    a2 = fmaf(w, Hs[s * 3 + 2], a2);
  }
  float r0 = scale * a0, r1 = scale * a1, r2 = scale * a2;
  if (Sub) { r0 -= Sub[r * 3 + 0]; r1 -= Sub[r * 3 + 1]; r2 -= Sub[r * 3 + 2]; }
  Out[r * 3 + 0] = r0; Out[r * 3 + 1] = r1; Out[r * 3 + 2] = r2;
}

// Chunk-major L2-resident prop pass. Buffers are [4][n][32] fp16; pass p's source
// chunk (n*64B = 3.2MB) fits each XCD L2. Lane layout: fo=(lane&7)*4 features,
// eo=lane>>3 edge slot (8). Per iter: 4 INDEPENDENT 8B gathers (32 edges).
// Streams (cw, Sub, out) use non-temporal ops so they don't evict the chunk.
// PHI: deferred phi(v)=sc*lrelu(v,slope)+sh on gathered values; Sub-phi via sst.
template <int PHI>
__global__ __launch_bounds__(256) void k_prop128c(
    const int* __restrict__ rowptr, const u64* __restrict__ cw8,
    const __half* __restrict__ PhC, const __half* __restrict__ SubC,
    __half* __restrict__ OutC, float scale, int n, int pass, float invn,
    const float* __restrict__ gst, const float* __restrict__ gg, const float* __restrict__ gbe,
    const float* __restrict__ sst, const float* __restrict__ sg, const float* __restrict__ sbe,
    float slope) {
  int r = blockIdx.x * 4 + (int)(threadIdx.x >> 6);
  int lane = threadIdx.x & 63;
  if (r >= n) return;
  int b = rowptr[r], e = rowptr[r + 1];
  int fo = (lane & 7) << 2;  // 4 features (8B)
  int eo = lane >> 3;        // edge slot 0..7
  const __half* srcC = PhC + (size_t)pass * n * 32;
  float a0 = 0.f, a1 = 0.f, a2 = 0.f, a3 = 0.f, ws = 0.f;
  for (int j = b; j < e; j += 32) {
    u64 hv[4];
    float w[4];
#pragma unroll
    for (int q = 0; q < 4; ++q) {
      int idx = j + q * 8 + eo;
      u64 m = (idx < e) ? __builtin_nontemporal_load(&cw8[idx]) : 0ull;
      w[q] = __uint_as_float((u32)(m >> 32));
      u32 s = (u32)m;
      hv[q] = *(const u64*)&srcC[(size_t)s * 32 + fo];
    }
#pragma unroll
    for (int q = 0; q < 4; ++q) {
      float2 f0 = u32f2((u32)hv[q]);
      float2 f1 = u32f2((u32)(hv[q] >> 32));
      if (PHI) {
        f0.x = lrelu(f0.x, slope); f0.y = lrelu(f0.y, slope);
        f1.x = lrelu(f1.x, slope); f1.y = lrelu(f1.y, slope);
        ws += w[q];
      }
      a0 = fmaf(w[q], f0.x, a0);
      a1 = fmaf(w[q], f0.y, a1);
      a2 = fmaf(w[q], f1.x, a2);
      a3 = fmaf(w[q], f1.y, a3);
    }
  }
#pragma unroll
  for (int mk = 8; mk <= 32; mk <<= 1) {
    a0 += __shfl_xor(a0, mk, 64);
    a1 += __shfl_xor(a1, mk, 64);
    a2 += __shfl_xor(a2, mk, 64);
    a3 += __shfl_xor(a3, mk, 64);
    if (PHI) ws += __shfl_xor(ws, mk, 64);
  }
  if (eo == 0) {
    int fg = pass * 32 + fo;
    float av[4] = {a0, a1, a2, a3};
    if (PHI) {
#pragma unroll
      for (int i = 0; i < 4; ++i) {
        float2 c = bn_coeff(gst, gg, gbe, invn, fg + i);
        av[i] = fmaf(av[i], c.x, ws * c.y);
      }
    }
#pragma unroll
    for (int i = 0; i < 4; ++i) av[i] *= scale;
    size_t off = (size_t)pass * n * 32 + (size_t)r * 32 + fo;
    if (SubC) {
      u64 sv = __builtin_nontemporal_load((const u64*)&SubC[off]);
      float2 s0 = u32f2((u32)sv);
      float2 s1 = u32f2((u32)(sv >> 32));
      float svf[4] = {s0.x, s0.y, s1.x, s1.y};
      if (sst != nullptr) {
#pragma unroll
        for (int i = 0; i < 4; ++i) {
          float2 d = bn_coeff(sst, sg, sbe, invn, fg + i);
          svf[i] = fmaf(lrelu(svf[i], slope), d.x, d.y);
        }
      }
#pragma unroll
      for (int i = 0; i < 4; ++i) av[i] -= svf[i];
    }
    u64 outv = (u64)f2u32(make_float2(av[0], av[1])) |
               ((u64)f2u32(make_float2(av[2], av[3])) << 32);
    __builtin_nontemporal_store(outv, (u64*)&OutC[off]);
  }
}

// ---------------- layer-1 fused gemm (fi=3) + BN stats, chunk-major fp16 out ----------------
__global__ __launch_bounds__(128) void k_l1gemm(
    const float* __restrict__ X, const float* __restrict__ T1, const float* __restrict__ T2,
    const float* __restrict__ T3, const float* __restrict__ W1, const float* __restrict__ b1,
    __half* __restrict__ OutC, float* __restrict__ bnsum, float* __restrict__ bnsq,
    float slope, int n, int rpb) {
  int j = threadIdx.x;
  float w[12];
#pragma unroll
  for (int t = 0; t < 4; ++t)
#pragma unroll
    for (int c = 0; c < 3; ++c) w[t * 3 + c] = W1[(t * 3 + c) * HD + j];
  float bj = b1[j];
  size_t obase = (size_t)(j >> 5) * n * 32 + (j & 31);
  int r0 = blockIdx.x * rpb, r1 = min(r0 + rpb, n);
  float s = 0.f, q = 0.f;
  for (int r = r0; r < r1; ++r) {
    float acc = bj;
#pragma unroll
    for (int c = 0; c < 3; ++c) {
      acc = fmaf(X [r * 3 + c], w[0 + c], acc);
      acc = fmaf(T1[r * 3 + c], w[3 + c], acc);
      acc = fmaf(T2[r * 3 + c], w[6 + c], acc);
      acc = fmaf(T3[r * 3 + c], w[9 + c], acc);
    }
    OutC[obase + (size_t)r * 32] = __float2half(acc);
    float a = lrelu(acc, slope);
    s += a;
    q = fmaf(a, a, q);
  }
  atomicAdd(&bnsum[j], s);
  atomicAdd(&bnsq[j], q);
}

// ---------------- W pre-split: fp32 -> fp16 hi/lo in MFMA frag-slot order ----------------
__global__ void k_wsplit3(const float* __restrict__ W2, const float* __restrict__ W3,
                          const float* __restrict__ W4, uint4* __restrict__ Whi,
                          uint4* __restrict__ Wlo) {
  int flat = blockIdx.x * 256 + threadIdx.x;  // 0..24575
  int wsel = flat >> 13;
  int f = flat & 8191;
  const float* W = (wsel == 0) ? W2 : (wsel == 1) ? W3 : W4;
  int n = f & 127, K8 = f >> 7;
  int chunk = K8 >> 2, g = K8 & 3;
  f16x8 hv, lv;
#pragma unroll
  for (int i = 0; i < 8; ++i) {
    int k = chunk * 32 + ((i >> 2) << 4) + g * 4 + (i & 3);
    float v = W[(size_t)k * HD + n];
    _Float16 hh = (_Float16)v;
    _Float16 hl = (_Float16)(v - (float)hh);
    hv[i] = hh;
    lv[i] = hl;
  }
  int slot = chunk * 512 + (n >> 4) * 64 + g * 16 + (n & 15);
  Whi[wsel * 8192 + slot] = *(uint4*)&hv;
  Wlo[wsel * 8192 + slot] = *(uint4*)&lv;
}

// ---------------- fused 4-term GEMM via fp16 MFMA, chunk-major feature I/O ----------------
// OUTh = fp16( bias + phi(T0)@W0 + T1@W1 + T2@W2 + T3@W3 ); optional fused BN stats.
// If outp != nullptr: epilogue does row-L2-normalize + @Wr + br -> outp instead.
__global__ __launch_bounds__(256) void k_gemm4m(
    const __half* __restrict__ T0, const __half* __restrict__ T1,
    const __half* __restrict__ T2, const __half* __restrict__ T3,
    const uint4* __restrict__ Whi, const uint4* __restrict__ Wlo,
    const float* __restrict__ bias, __half* __restrict__ OUTh,
    float* bnsum, float* bnsq, float stat_slope,
    const float* __restrict__ gst, const float* __restrict__ gg,
    const float* __restrict__ gbe, float invn, float phi_slope,
    const float* __restrict__ Wr, const float* __restrict__ br, float* __restrict__ outp,
    int nrows) {
  __shared__ __half sA[2048];              // 256 slots x 8 fp16
  __shared__ __half sWh[4096], sWl[4096];  // 512 slots x 8 fp16 each
  __shared__ float redS[128], redQ[128];
  __shared__ float fss[64];
  __shared__ float fob[64][3];

  int tid = threadIdx.x;
  int lane = tid & 63, w = tid >> 6, wr = w >> 1, wc = w & 1;
  int g = (tid >> 4) & 3;
  int ri = tid & 15;
  int row0 = blockIdx.x * 64;
  int arow = row0 + w * 16 + ri;
  bool aval = arow < nrows;

  f32x4 zero = {0.f, 0.f, 0.f, 0.f};
  f32x4 acc[2][4];
#pragma unroll
  for (int mi = 0; mi < 2; ++mi)
#pragma unroll
    for (int nj = 0; nj < 4; ++nj) acc[mi][nj] = zero;

  if (tid < 128) { redS[tid] = 0.f; redQ[tid] = 0.f; }
  if (tid < 64) { fss[tid] = 0.f; fob[tid][0] = 0.f; fob[tid][1] = 0.f; fob[tid][2] = 0.f; }

  for (int chunk = 0; chunk < 16; ++chunk) {
    const __half* Ts = (chunk < 4) ? T0 : (chunk < 8) ? T1 : (chunk < 12) ? T2 : T3;
    int kc = chunk & 3;
    h4s va, vb;
    *(uint2*)&va = make_uint2(0u, 0u);
    *(uint2*)&vb = make_uint2(0u, 0u);
    if (aval) {
      const __half* ap = Ts + ((size_t)kc * nrows + arow) * 32 + g * 4;
      va = *(const h4s*)ap;
      vb = *(const h4s*)(ap + 16);
    }
    size_t wbase = (size_t)chunk * 512;
    uint4 wh0 = Whi[wbase + tid], wh1 = Whi[wbase + 256 + tid];
    uint4 wl0 = Wlo[wbase + tid], wl1 = Wlo[wbase + 256 + tid];

    __syncthreads();

    if (gst != nullptr && chunk < 4) {
      float fv[8];
      float2 f0 = __half22float2(va.a), f1 = __half22float2(va.b);
      float2 f2 = __half22float2(vb.a), f3 = __half22float2(vb.b);
      fv[0] = f0.x; fv[1] = f0.y; fv[2] = f1.x; fv[3] = f1.y;
      fv[4] = f2.x; fv[5] = f2.y; fv[6] = f3.x; fv[7] = f3.y;
#pragma unroll
      for (int i = 0; i < 8; ++i) {
        int f = kc * 32 + g * 4 + (i & 3) + ((i >> 2) << 4);
        float2 cs = bn_coeff(gst, gg, gbe, invn, f);
        fv[i] = fmaf(lrelu(fv[i], phi_slope), cs.x, cs.y);
      }
      va.a = __float22half2_rn(make_float2(fv[0], fv[1]));
      va.b = __float22half2_rn(make_float2(fv[2], fv[3]));
      vb.a = __float22half2_rn(make_float2(fv[4], fv[5]));
      vb.b = __float22half2_rn(make_float2(fv[6], fv[7]));
    }
    *(h4s*)&sA[tid * 8] = va;
    *(h4s*)&sA[tid * 8 + 4] = vb;
    *(uint4*)&sWh[tid * 8] = wh0;
    *(uint4*)&sWh[(256 + tid) * 8] = wh1;
    *(uint4*)&sWl[tid * 8] = wl0;
    *(uint4*)&sWl[(256 + tid) * 8] = wl1;
    __syncthreads();

    f16x8 a[2], bh[4], bl[4];
#pragma unroll
    for (int mi = 0; mi < 2; ++mi)
      a[mi] = *(const f16x8*)&sA[((wr * 2 + mi) * 64 + lane) * 8];
#pragma unroll
    for (int nj = 0; nj < 4; ++nj) {
      bh[nj] = *(const f16x8*)&sWh[((wc * 4 + nj) * 64 + lane) * 8];
      bl[nj] = *(const f16x8*)&sWl[((wc * 4 + nj) * 64 + lane) * 8];
    }
#pragma unroll
    for (int mi = 0; mi < 2; ++mi)
#pragma unroll
      for (int nj = 0; nj < 4; ++nj) {
        acc[mi][nj] = __builtin_amdgcn_mfma_f32_16x16x32_f16(a[mi], bh[nj], acc[mi][nj], 0, 0, 0);
        acc[mi][nj] = __builtin_amdgcn_mfma_f32_16x16x32_f16(a[mi], bl[nj], acc[mi][nj], 0, 0, 0);
      }
  }

  int l4 = (lane >> 4) * 4, ni = lane & 15;

  if (outp == nullptr) {
    bool stats = (bnsum != nullptr);
#pragma unroll
    for (int nj = 0; nj < 4; ++nj) {
      int c = wc * 64 + nj * 16 + ni;
      float bcol = bias[c];
      size_t obase = (size_t)(c >> 5) * nrows * 32 + (c & 31);
      float s = 0.f, q = 0.f;
#pragma unroll
      for (int mi = 0; mi < 2; ++mi)
#pragma unroll
        for (int j = 0; j < 4; ++j) {
          int row = row0 + (wr * 2 + mi) * 16 + l4 + j;
          if (row < nrows) {
            float v = acc[mi][nj][j] + bcol;
            OUTh[obase + (size_t)row * 32] = __float2half(v);
            if (stats) {
              float a = lrelu(v, stat_slope);
              s += a;
              q = fmaf(a, a, q);
            }
          }
        }
      if (stats) {
        s += __shfl_xor(s, 16, 64);
        s += __shfl_xor(s, 32, 64);
        q += __shfl_xor(q, 16, 64);
        q += __shfl_xor(q, 32, 64);
        if (lane < 16) {
          atomicAdd(&redS[c], s);
          atomicAdd(&redQ[c], q);
        }
      }
    }
    if (stats) {
      __syncthreads();
      if (tid < 128) {
        atomicAdd(&bnsum[tid], redS[tid]);
        atomicAdd(&bnsq[tid], redQ[tid]);
      }
    }
  } else {
    // fused final: row L2-normalize + @Wr + br -> outp
    __syncthreads();
    float ss8[2][4];
#pragma unroll
    for (int mi = 0; mi < 2; ++mi)
#pragma unroll
      for (int j = 0; j < 4; ++j) ss8[mi][j] = 0.f;
#pragma unroll
    for (int nj = 0; nj < 4; ++nj) {
      int c = wc * 64 + nj * 16 + ni;
      float bcol = bias[c];
#pragma unroll
      for (int mi = 0; mi < 2; ++mi)
#pragma unroll
        for (int j = 0; j < 4; ++j) {
          float v = acc[mi][nj][j] + bcol;
          ss8[mi][j] = fmaf(v, v, ss8[mi][j]);
        }
    }
#pragma unroll
    for (int mk = 1; mk <= 8; mk <<= 1)
#pragma unroll
      for (int mi = 0; mi < 2; ++mi)
#pragma unroll
        for (int j = 0; j < 4; ++j) ss8[mi][j] += __shfl_xor(ss8[mi][j], mk, 64);
    if (ni == 0) {
#pragma unroll
      for (int mi = 0; mi < 2; ++mi)
#pragma unroll
        for (int j = 0; j < 4; ++j)
          atomicAdd(&fss[(wr * 2 + mi) * 16 + l4 + j], ss8[mi][j]);
    }
    __syncthreads();
    if (tid < 64) fss[tid] = 1.f / fmaxf(sqrtf(fss[tid]), 1e-12f);
    __syncthreads();
#pragma unroll
    for (int mi = 0; mi < 2; ++mi)
#pragma unroll
      for (int j = 0; j < 4; ++j) {
        int rl = (wr * 2 + mi) * 16 + l4 + j;
        float inv = fss[rl];
        float o0 = 0.f, o1 = 0.f, o2 = 0.f;
#pragma unroll
        for (int nj = 0; nj < 4; ++nj) {
          int c = wc * 64 + nj * 16 + ni;
          float v = (acc[mi][nj][j] + bias[c]) * inv;
          o0 = fmaf(v, Wr[c * 3 + 0], o0);
          o1 = fmaf(v, Wr[c * 3 + 1], o1);
          o2 = fmaf(v, Wr[c * 3 + 2], o2);
        }
#pragma unroll
        for (int mk = 1; mk <= 8; mk <<= 1) {
          o0 += __shfl_xor(o0, mk, 64);
          o1 += __shfl_xor(o1, mk, 64);
          o2 += __shfl_xor(o2, mk, 64);
        }
        if (ni == 0) {
          atomicAdd(&fob[rl][0], o0);
          atomicAdd(&fob[rl][1], o1);
          atomicAdd(&fob[rl][2], o2);
        }
      }
    __syncthreads();
    if (tid < 64) {
      int row = row0 + tid;
      if (row < nrows) {
        outp[row * 3 + 0] = fob[tid][0] + br[0];
        outp[row * 3 + 1] = fob[tid][1] + br[1];
        outp[row * 3 + 2] = fob[tid][2] + br[2];
      }
    }
  }
}

extern "C" void kernel_launch(void* const* d_in, const int* in_sizes, int n_in,
                              void* d_out, int out_size, void* d_ws, size_t ws_size,
                              hipStream_t stream) {
  const float* x  = (const float*)d_in[0];
  const int*   ei = (const int*)d_in[1];
  const float* W1 = (const float*)d_in[2];
  const float* b1 = (const float*)d_in[3];
  const float* W2 = (const float*)d_in[4];
  const float* b2 = (const float*)d_in[5];
  const float* W3 = (const float*)d_in[6];
  const float* b3 = (const float*)d_in[7];
  const float* W4 = (const float*)d_in[8];
  const float* b4 = (const float*)d_in[9];
  const float* g1 = (const float*)d_in[10];
  const float* be1= (const float*)d_in[11];
  const float* g2 = (const float*)d_in[12];
  const float* be2= (const float*)d_in[13];
  const float* g3 = (const float*)d_in[14];
  const float* be3= (const float*)d_in[15];
  const float* Wr = (const float*)d_in[16];
  const float* br = (const float*)d_in[17];

  const int N = in_sizes[0] / 3;
  const int E = in_sizes[1] / 2;
  const int* src = ei;
  const int* dst = ei + E;
  float* out = (float*)d_out;
  const float invn = 1.0f / (float)N;

  char* wp = (char*)d_ws;
  size_t used = 0;
  auto alloc = [&](size_t bytes) -> void* {
    void* p = (void*)(wp + used);
    used += (bytes + 255) & ~(size_t)255;
    return p;
  };
  int*   deg2   = (int*)alloc((size_t)2 * N * 4);
  int*   rowptr = (int*)alloc((size_t)(N + 1) * 4);
  float* dinv   = (float*)alloc((size_t)N * 4);
  int*   bsums  = (int*)alloc(256 * 4);
  int*   ledge  = (int*)alloc((size_t)E * 4);
  uint2* cw     = (uint2*)alloc((size_t)E * 8);
  float* t1     = (float*)alloc((size_t)N * 3 * 4);
  float* t2     = (float*)alloc((size_t)N * 3 * 4);
  float* t3     = (float*)alloc((size_t)N * 3 * 4);
  __half* phA   = (__half*)alloc((size_t)N * HD * 2);
  __half* phB   = (__half*)alloc((size_t)N * HD * 2);
  __half* phC   = (__half*)alloc((size_t)N * HD * 2);
  __half* phD   = (__half*)alloc((size_t)N * HD * 2);
  float* stats  = (float*)alloc(6 * HD * 4);  // [sum1,sq1,sum2,sq2,sum3,sq3]
  uint4* Whi3   = (uint4*)alloc(3 * 8192 * 16);
  uint4* Wlo3   = (uint4*)alloc(3 * 8192 * 16);
  if (used > ws_size) return;

  int* degc = deg2;
  int* cnt  = deg2 + N;
  float* st1 = stats + 0 * HD;
  float* st2 = stats + 2 * HD;
  float* st3 = stats + 4 * HD;

  const int eb = (E + 255) / 256;
  const int nb = (N + 255) / 256;
  const int pb = (N + 3) / 4;
  const int sb = (N + 1023) / 1024;
  const int gbm = (N + 63) / 64;

  hipMemsetAsync(deg2, 0, (size_t)2 * N * 4, stream);
  k_edge_count<<<eb, 256, 0, stream>>>(src, dst, degc, cnt, ledge, E);
  k_scan1<<<sb, 1024, 0, stream>>>(cnt, rowptr, bsums, stats, N);
  k_scan3<<<sb, 1024, 0, stream>>>(rowptr, bsums, degc, dinv, N, E, sb);
  k_fill<<<eb, 256, 0, stream>>>(src, dst, ledge, rowptr, dinv, cw, E);
  k_wsplit3<<<96, 256, 0, stream>>>(W2, W3, W4, Whi3, Wlo3);

  // ---- layer 1 (fi=3) ----
  k_prop3<<<nb, 256, 0, stream>>>(rowptr, cw, x, nullptr, t1, 1.f, N);
  k_prop3<<<nb, 256, 0, stream>>>(rowptr, cw, t1, x, t2, 2.f, N);
  k_prop3<<<nb, 256, 0, stream>>>(rowptr, cw, t2, t1, t3, 2.f, N);
  k_l1gemm<<<(N + 255) / 256, 128, 0, stream>>>(x, t1, t2, t3, W1, b1, phA,
                                                st1, st1 + HD, 0.01f, N, 256);

  const u64* cw8 = (const u64*)cw;

  // ---- layers 2..4 (chunk-major fp16 H in phA; phi from raw stats at consumers) ----
  auto cheb_layer = [&](const uint4* Whi, const uint4* Wlo, const float* bk,
                        const float* gst, const float* gg, const float* gbe, float phi_slope,
                        float* so, float stat_slope,
                        const float* Wrp, const float* brp, float* outp) {
    for (int p = 0; p < 4; ++p)  // T1 = L*phi(H)
      k_prop128c<1><<<pb, 256, 0, stream>>>(rowptr, cw8, phA, nullptr, phB, 1.f, N, p, invn,
                                            gst, gg, gbe, nullptr, nullptr, nullptr, phi_slope);
    for (int p = 0; p < 4; ++p)  // T2 = 2L*T1 - phi(H)
      k_prop128c<0><<<pb, 256, 0, stream>>>(rowptr, cw8, phB, phA, phC, 2.f, N, p, invn,
                                            nullptr, nullptr, nullptr, gst, gg, gbe, phi_slope);
    for (int p = 0; p < 4; ++p)  // T3 = 2L*T2 - T1
      k_prop128c<0><<<pb, 256, 0, stream>>>(rowptr, cw8, phC, phB, phD, 2.f, N, p, invn,
                                            nullptr, nullptr, nullptr, nullptr, nullptr,
                                            nullptr, 0.f);
    k_gemm4m<<<gbm, 256, 0, stream>>>(phA, phB, phC, phD, Whi, Wlo, bk, phA,
                                      so, so ? so + HD : nullptr, stat_slope,
                                      gst, gg, gbe, invn, phi_slope,
                                      Wrp, brp, outp, N);
  };

  cheb_layer(Whi3, Wlo3, b2, st1, g1, be1, 0.01f, st2, 0.01f, nullptr, nullptr, nullptr);
  cheb_layer(Whi3 + 8192, Wlo3 + 8192, b3, st2, g2, be2, 0.01f, st3, 0.0f,
             nullptr, nullptr, nullptr);
  cheb_layer(Whi3 + 16384, Wlo3 + 16384, b4, st3, g3, be3, 0.0f, nullptr, 0.0f, Wr, br, out);
}

// Round 15
// 752.357 us; speedup vs baseline: 1.7647x; 1.7647x over previous
//
#include <hip/hip_runtime.h>
#include <hip/hip_fp16.h>

#define HD 128

typedef __attribute__((ext_vector_type(8))) _Float16 f16x8;
typedef __attribute__((ext_vector_type(4))) float f32x4;
typedef unsigned int u32;
typedef unsigned long long u64;

struct h4s { __half2 a, b; };  // 4 fp16 = 8 B

__device__ __forceinline__ float lrelu(float x, float s) { return x > 0.f ? x : s * x; }

__device__ __forceinline__ float2 u32f2(u32 v) {
  __half2 h;
  *reinterpret_cast<u32*>(&h) = v;
  return __half22float2(h);
}
__device__ __forceinline__ u32 f2u32(float2 f) {
  __half2 h = __float22half2_rn(f);
  return *reinterpret_cast<u32*>(&h);
}

// BN scale/shift from raw stats: st[f]=sum, st[HD+f]=sumsq
__device__ __forceinline__ float2 bn_coeff(const float* st, const float* g,
                                           const float* be, float invn, int f) {
  float m = st[f] * invn;
  float v = st[HD + f] * invn - m * m;
  float sc = g[f] * rsqrtf(v + 1e-5f);
  return make_float2(sc, be[f] - m * sc);
}

// ---------------- graph prep ----------------
// packed dual histogram: lo16 = out-degree (by src), hi16 = in-degree (by dst).
// Halves distinct atomic lines vs two arrays (less cross-XCD ping-pong).
__global__ void k_edge_count(const int* __restrict__ src, const int* __restrict__ dst,
                             u32* __restrict__ packed, int* __restrict__ ledge, int E) {
  int e = blockIdx.x * blockDim.x + threadIdx.x;
  if (e < E) {
    atomicAdd(&packed[src[e]], 1u);
    u32 old = atomicAdd(&packed[dst[e]], 0x10000u);
    ledge[e] = (int)(old >> 16);
  }
}

// scan of in-degrees (hi16 of packed); + zero the BN stats buffer (block 0)
__global__ __launch_bounds__(1024) void k_scan1(const u32* __restrict__ packed,
                                                int* __restrict__ rowptr,
                                                int* __restrict__ bsums,
                                                float* __restrict__ stats, int n) {
  if (blockIdx.x == 0 && threadIdx.x < 6 * HD) stats[threadIdx.x] = 0.f;
  __shared__ int buf[1024];
  int i = blockIdx.x * 1024 + threadIdx.x;
  int v = (i < n) ? (int)(packed[i] >> 16) : 0;
  buf[threadIdx.x] = v;
  __syncthreads();
  for (int o = 1; o < 1024; o <<= 1) {
    int t = (threadIdx.x >= (unsigned)o) ? buf[threadIdx.x - o] : 0;
    __syncthreads();
    buf[threadIdx.x] += t;
    __syncthreads();
  }
  if (i < n) rowptr[i] = buf[threadIdx.x] - v;
  if (threadIdx.x == 1023) bsums[blockIdx.x] = buf[1023];
}

__global__ __launch_bounds__(1024) void k_scan3(int* __restrict__ rowptr,
                                                const int* __restrict__ bsums,
                                                const u32* __restrict__ packed,
                                                float* __restrict__ dinv, int n, int Etot,
                                                int nb) {
  __shared__ int blockoff;
  if (nb <= 64) {
    if (threadIdx.x < 64) {
      int lane = threadIdx.x;
      int v = (lane < nb) ? bsums[lane] : 0;
      int inc = v;
#pragma unroll
      for (int o = 1; o < 64; o <<= 1) {
        int t = __shfl_up(inc, o, 64);
        if (lane >= o) inc += t;
      }
      if (lane == (int)blockIdx.x) blockoff = inc - v;
    }
  } else if (threadIdx.x == 0) {
    int sum = 0;
    for (int t = 0; t < (int)blockIdx.x; ++t) sum += bsums[t];
    blockoff = sum;
  }
  __syncthreads();
  int i = blockIdx.x * 1024 + threadIdx.x;
  if (i < n) {
    rowptr[i] += blockoff;
    int dg = (int)(packed[i] & 0xffffu);
    dinv[i] = dg > 0 ? rsqrtf((float)dg) : 0.f;
  }
  if (i == 0) rowptr[n] = Etot;
}

// atomic-free CSR fill
__global__ void k_fill(const int* __restrict__ src, const int* __restrict__ dst,
                       const int* __restrict__ ledge, const int* __restrict__ rowptr,
                       const float* __restrict__ dinv, uint2* __restrict__ cw, int E) {
  int e = blockIdx.x * blockDim.x + threadIdx.x;
  if (e < E) {
    int s = src[e], d = dst[e];
    int p = rowptr[d] + ledge[e];
    cw[p] = make_uint2((u32)s, __float_as_uint(-dinv[s] * dinv[d]));
  }
}

// ---------------- props ----------------
__global__ void k_prop3(const int* __restrict__ rowptr, const uint2* __restrict__ cw,
                        const float* __restrict__ Hs, const float* __restrict__ Sub,
                        float* __restrict__ Out, float scale, int n) {
  int r = blockIdx.x * blockDim.x + threadIdx.x;
  if (r >= n) return;
  int b = rowptr[r], e = rowptr[r + 1];
  float a0 = 0.f, a1 = 0.f, a2 = 0.f;
  for (int j = b; j < e; ++j) {
    uint2 m = cw[j];
    int s = (int)m.x;
    float w = __uint_as_float(m.y);
    a0 = fmaf(w, Hs[s * 3 + 0], a0);
    a1 = fmaf(w, Hs[s * 3 + 1], a1);
    a2 = fmaf(w, Hs[s * 3 + 2], a2);
  }
  float r0 = scale * a0, r1 = scale * a1, r2 = scale * a2;
  if (Sub) { r0 -= Sub[r * 3 + 0]; r1 -= Sub[r * 3 + 1]; r2 -= Sub[r * 3 + 2]; }
  Out[r * 3 + 0] = r0; Out[r * 3 + 1] = r1; Out[r * 3 + 2] = r2;
}

// F=128 prop, fp16 feature I/O, fp32 accumulation (round-12 structure: one wave per
// dst row, half-wave 8B gathers, 4 gathers in flight). NT loads/stores on the
// single-touch streams (cw, Sub, out) so they don't evict the gather source from L2.
// PHI: deferred phi(v)=sc*lrelu(v,slope)+sh on gathered values (coeffs from raw BN
// stats gst/gg/gbe); Sub-phi likewise via (sst,sg,sbe) when non-null.
template <int PHI>
__global__ __launch_bounds__(256) void k_prop128(
    const int* __restrict__ rowptr, const u64* __restrict__ cw8,
    const __half* __restrict__ Ph, const __half* __restrict__ Sub,
    __half* __restrict__ Outh, float scale, int n, float invn,
    const float* __restrict__ gst, const float* __restrict__ gg, const float* __restrict__ gbe,
    const float* __restrict__ sst, const float* __restrict__ sg, const float* __restrict__ sbe,
    float slope) {
  int r = blockIdx.x * 4 + (int)(threadIdx.x >> 6);
  int lane = threadIdx.x & 63;
  if (r >= n) return;
  int b = rowptr[r], e = rowptr[r + 1];
  int fl = (lane & 31) << 2;
  int half = lane >> 5;
  float ax = 0.f, ay = 0.f, az = 0.f, aw = 0.f, ws = 0.f;
  int j = b;
  for (; j + 7 < e; j += 8) {
    u64 hv[4];
    float w[4];
#pragma unroll
    for (int q = 0; q < 4; ++q) {
      int idx = j + 2 * q + half;
      u64 m = __builtin_nontemporal_load(&cw8[idx]);
      w[q] = __uint_as_float((u32)(m >> 32));
      hv[q] = *(const u64*)&Ph[(size_t)(u32)m * HD + fl];
    }
#pragma unroll
    for (int q = 0; q < 4; ++q) {
      float2 f0 = u32f2((u32)hv[q]);
      float2 f1 = u32f2((u32)(hv[q] >> 32));
      if (PHI) {
        f0.x = lrelu(f0.x, slope); f0.y = lrelu(f0.y, slope);
        f1.x = lrelu(f1.x, slope); f1.y = lrelu(f1.y, slope);
        ws += w[q];
      }
      ax = fmaf(w[q], f0.x, ax);
      ay = fmaf(w[q], f0.y, ay);
      az = fmaf(w[q], f1.x, az);
      aw = fmaf(w[q], f1.y, aw);
    }
  }
  for (; j + 1 < e; j += 2) {
    int idx = j + half;
    u64 m = __builtin_nontemporal_load(&cw8[idx]);
    float w = __uint_as_float((u32)(m >> 32));
    u64 hv = *(const u64*)&Ph[(size_t)(u32)m * HD + fl];
    float2 f0 = u32f2((u32)hv);
    float2 f1 = u32f2((u32)(hv >> 32));
    if (PHI) {
      f0.x = lrelu(f0.x, slope); f0.y = lrelu(f0.y, slope);
      f1.x = lrelu(f1.x, slope); f1.y = lrelu(f1.y, slope);
      ws += w;
    }
    ax = fmaf(w, f0.x, ax);
    ay = fmaf(w, f0.y, ay);
    az = fmaf(w, f1.x, az);
    aw = fmaf(w, f1.y, aw);
  }
  if (j < e && half == 0) {
    u64 m = __builtin_nontemporal_load(&cw8[j]);
    float w = __uint_as_float((u32)(m >> 32));
    u64 hv = *(const u64*)&Ph[(size_t)(u32)m * HD + fl];
    float2 f0 = u32f2((u32)hv);
    float2 f1 = u32f2((u32)(hv >> 32));
    if (PHI) {
      f0.x = lrelu(f0.x, slope); f0.y = lrelu(f0.y, slope);
      f1.x = lrelu(f1.x, slope); f1.y = lrelu(f1.y, slope);
      ws += w;
    }
    ax = fmaf(w, f0.x, ax);
    ay = fmaf(w, f0.y, ay);
    az = fmaf(w, f1.x, az);
    aw = fmaf(w, f1.y, aw);
  }
  ax += __shfl_xor(ax, 32, 64);
  ay += __shfl_xor(ay, 32, 64);
  az += __shfl_xor(az, 32, 64);
  aw += __shfl_xor(aw, 32, 64);
  if (PHI) {
    ws += __shfl_xor(ws, 32, 64);
    float2 c0 = bn_coeff(gst, gg, gbe, invn, fl + 0);
    float2 c1 = bn_coeff(gst, gg, gbe, invn, fl + 1);
    float2 c2 = bn_coeff(gst, gg, gbe, invn, fl + 2);
    float2 c3 = bn_coeff(gst, gg, gbe, invn, fl + 3);
    ax = fmaf(ax, c0.x, ws * c0.y);
    ay = fmaf(ay, c1.x, ws * c1.y);
    az = fmaf(az, c2.x, ws * c2.y);
    aw = fmaf(aw, c3.x, ws * c3.y);
  }
  float4 o = make_float4(scale * ax, scale * ay, scale * az, scale * aw);
  if (Sub && half == 0) {
    u64 sv = __builtin_nontemporal_load((const u64*)&Sub[(size_t)r * HD + fl]);
    float2 s0 = u32f2((u32)sv);
    float2 s1 = u32f2((u32)(sv >> 32));
    float svf[4] = {s0.x, s0.y, s1.x, s1.y};
    if (sst != nullptr) {
#pragma unroll
      for (int i = 0; i < 4; ++i) {
        float2 d = bn_coeff(sst, sg, sbe, invn, fl + i);
        svf[i] = fmaf(lrelu(svf[i], slope), d.x, d.y);
      }
    }
    o.x -= svf[0]; o.y -= svf[1]; o.z -= svf[2]; o.w -= svf[3];
  }
  if (half == 0) {
    u64 outv = (u64)f2u32(make_float2(o.x, o.y)) |
               ((u64)f2u32(make_float2(o.z, o.w)) << 32);
    __builtin_nontemporal_store(outv, (u64*)&Outh[(size_t)r * HD + fl]);
  }
}

// ---------------- layer-1 fused gemm (fi=3, K=4) + fused BN stats, fp16 out ----------------
__global__ __launch_bounds__(128) void k_l1gemm(
    const float* __restrict__ X, const float* __restrict__ T1, const float* __restrict__ T2,
    const float* __restrict__ T3, const float* __restrict__ W1, const float* __restrict__ b1,
    __half* __restrict__ Outh, float* __restrict__ bnsum, float* __restrict__ bnsq,
    float slope, int n, int rpb) {
  int j = threadIdx.x;
  float w[12];
#pragma unroll
  for (int t = 0; t < 4; ++t)
#pragma unroll
    for (int c = 0; c < 3; ++c) w[t * 3 + c] = W1[(t * 3 + c) * HD + j];
  float bj = b1[j];
  int r0 = blockIdx.x * rpb, r1 = min(r0 + rpb, n);
  float s = 0.f, q = 0.f;
  for (int r = r0; r < r1; ++r) {
    float acc = bj;
#pragma unroll
    for (int c = 0; c < 3; ++c) {
      acc = fmaf(X [r * 3 + c], w[0 + c], acc);
      acc = fmaf(T1[r * 3 + c], w[3 + c], acc);
      acc = fmaf(T2[r * 3 + c], w[6 + c], acc);
      acc = fmaf(T3[r * 3 + c], w[9 + c], acc);
    }
    Outh[(size_t)r * HD + j] = __float2half(acc);
    float a = lrelu(acc, slope);
    s += a;
    q = fmaf(a, a, q);
  }
  atomicAdd(&bnsum[j], s);
  atomicAdd(&bnsq[j], q);
}

// ---------------- W pre-split: fp32 -> fp16 hi/lo in MFMA frag-slot order ----------------
__global__ void k_wsplit3(const float* __restrict__ W2, const float* __restrict__ W3,
                          const float* __restrict__ W4, uint4* __restrict__ Whi,
                          uint4* __restrict__ Wlo) {
  int flat = blockIdx.x * 256 + threadIdx.x;  // 0..24575
  int wsel = flat >> 13;
  int f = flat & 8191;
  const float* W = (wsel == 0) ? W2 : (wsel == 1) ? W3 : W4;
  int n = f & 127, K8 = f >> 7;
  int chunk = K8 >> 2, g = K8 & 3;
  f16x8 hv, lv;
#pragma unroll
  for (int i = 0; i < 8; ++i) {
    int k = chunk * 32 + ((i >> 2) << 4) + g * 4 + (i & 3);
    float v = W[(size_t)k * HD + n];
    _Float16 hh = (_Float16)v;
    _Float16 hl = (_Float16)(v - (float)hh);
    hv[i] = hh;
    lv[i] = hl;
  }
  int slot = chunk * 512 + (n >> 4) * 64 + g * 16 + (n & 15);
  Whi[wsel * 8192 + slot] = *(uint4*)&hv;
  Wlo[wsel * 8192 + slot] = *(uint4*)&lv;
}

// ---------------- fused 4-term GEMM via fp16 MFMA (A exact, W 2-term) ----------------
// OUTh = fp16( bias + phi(T0)@W0 + T1@W1 + T2@W2 + T3@W3 ); optional fused BN stats.
// If outp != nullptr: epilogue does row-L2-normalize + @Wr + br -> outp instead.
__global__ __launch_bounds__(256) void k_gemm4m(
    const __half* __restrict__ T0, const __half* __restrict__ T1,
    const __half* __restrict__ T2, const __half* __restrict__ T3,
    const uint4* __restrict__ Whi, const uint4* __restrict__ Wlo,
    const float* __restrict__ bias, __half* __restrict__ OUTh,
    float* bnsum, float* bnsq, float stat_slope,
    const float* __restrict__ gst, const float* __restrict__ gg,
    const float* __restrict__ gbe, float invn, float phi_slope,
    const float* __restrict__ Wr, const float* __restrict__ br, float* __restrict__ outp,
    int nrows) {
  __shared__ __half sA[2048];              // 256 slots x 8 fp16
  __shared__ __half sWh[4096], sWl[4096];  // 512 slots x 8 fp16 each
  __shared__ float redS[128], redQ[128];
  __shared__ float fss[64];
  __shared__ float fob[64][3];

  int tid = threadIdx.x;
  int lane = tid & 63, w = tid >> 6, wr = w >> 1, wc = w & 1;
  int g = (tid >> 4) & 3;
  int ri = tid & 15;
  int row0 = blockIdx.x * 64;
  int arow = row0 + w * 16 + ri;
  bool aval = arow < nrows;

  f32x4 zero = {0.f, 0.f, 0.f, 0.f};
  f32x4 acc[2][4];
#pragma unroll
  for (int mi = 0; mi < 2; ++mi)
#pragma unroll
    for (int nj = 0; nj < 4; ++nj) acc[mi][nj] = zero;

  if (tid < 128) { redS[tid] = 0.f; redQ[tid] = 0.f; }
  if (tid < 64) { fss[tid] = 0.f; fob[tid][0] = 0.f; fob[tid][1] = 0.f; fob[tid][2] = 0.f; }

  for (int chunk = 0; chunk < 16; ++chunk) {
    const __half* Ts = (chunk < 4) ? T0 : (chunk < 8) ? T1 : (chunk < 12) ? T2 : T3;
    int kc = chunk & 3;
    h4s va, vb;
    *(uint2*)&va = make_uint2(0u, 0u);
    *(uint2*)&vb = make_uint2(0u, 0u);
    if (aval) {
      const __half* ap = Ts + (size_t)arow * HD + kc * 32 + g * 4;
      va = *(const h4s*)ap;
      vb = *(const h4s*)(ap + 16);
    }
    size_t wbase = (size_t)chunk * 512;
    uint4 wh0 = Whi[wbase + tid], wh1 = Whi[wbase + 256 + tid];
    uint4 wl0 = Wlo[wbase + tid], wl1 = Wlo[wbase + 256 + tid];

    __syncthreads();

    if (gst != nullptr && chunk < 4) {
      float fv[8];
      float2 f0 = __half22float2(va.a), f1 = __half22float2(va.b);
      float2 f2 = __half22float2(vb.a), f3 = __half22float2(vb.b);
      fv[0] = f0.x; fv[1] = f0.y; fv[2] = f1.x; fv[3] = f1.y;
      fv[4] = f2.x; fv[5] = f2.y; fv[6] = f3.x; fv[7] = f3.y;
#pragma unroll
      for (int i = 0; i < 8; ++i) {
        int f = kc * 32 + g * 4 + (i & 3) + ((i >> 2) << 4);
        float2 cs = bn_coeff(gst, gg, gbe, invn, f);
        fv[i] = fmaf(lrelu(fv[i], phi_slope), cs.x, cs.y);
      }
      va.a = __float22half2_rn(make_float2(fv[0], fv[1]));
      va.b = __float22half2_rn(make_float2(fv[2], fv[3]));
      vb.a = __float22half2_rn(make_float2(fv[4], fv[5]));
      vb.b = __float22half2_rn(make_float2(fv[6], fv[7]));
    }
    *(h4s*)&sA[tid * 8] = va;
    *(h4s*)&sA[tid * 8 + 4] = vb;
    *(uint4*)&sWh[tid * 8] = wh0;
    *(uint4*)&sWh[(256 + tid) * 8] = wh1;
    *(uint4*)&sWl[tid * 8] = wl0;
    *(uint4*)&sWl[(256 + tid) * 8] = wl1;
    __syncthreads();

    f16x8 a[2], bh[4], bl[4];
#pragma unroll
    for (int mi = 0; mi < 2; ++mi)
      a[mi] = *(const f16x8*)&sA[((wr * 2 + mi) * 64 + lane) * 8];
#pragma unroll
    for (int nj = 0; nj < 4; ++nj) {
      bh[nj] = *(const f16x8*)&sWh[((wc * 4 + nj) * 64 + lane) * 8];
      bl[nj] = *(const f16x8*)&sWl[((wc * 4 + nj) * 64 + lane) * 8];
    }
#pragma unroll
    for (int mi = 0; mi < 2; ++mi)
#pragma unroll
      for (int nj = 0; nj < 4; ++nj) {
        acc[mi][nj] = __builtin_amdgcn_mfma_f32_16x16x32_f16(a[mi], bh[nj], acc[mi][nj], 0, 0, 0);
        acc[mi][nj] = __builtin_amdgcn_mfma_f32_16x16x32_f16(a[mi], bl[nj], acc[mi][nj], 0, 0, 0);
      }
  }

  int l4 = (lane >> 4) * 4, ni = lane & 15;

  if (outp == nullptr) {
    bool stats = (bnsum != nullptr);
#pragma unroll
    for (int nj = 0; nj < 4; ++nj) {
      int c = wc * 64 + nj * 16 + ni;
      float bcol = bias[c];
      float s = 0.f, q = 0.f;
#pragma unroll
      for (int mi = 0; mi < 2; ++mi)
#pragma unroll
        for (int j = 0; j < 4; ++j) {
          int row = row0 + (wr * 2 + mi) * 16 + l4 + j;
          if (row < nrows) {
            float v = acc[mi][nj][j] + bcol;
            OUTh[(size_t)row * HD + c] = __float2half(v);
            if (stats) {
              float a = lrelu(v, stat_slope);
              s += a;
              q = fmaf(a, a, q);
            }
          }
        }
      if (stats) {
        s += __shfl_xor(s, 16, 64);
        s += __shfl_xor(s, 32, 64);
        q += __shfl_xor(q, 16, 64);
        q += __shfl_xor(q, 32, 64);
        if (lane < 16) {
          atomicAdd(&redS[c], s);
          atomicAdd(&redQ[c], q);
        }
      }
    }
    if (stats) {
      __syncthreads();
      if (tid < 128) {
        atomicAdd(&bnsum[tid], redS[tid]);
        atomicAdd(&bnsq[tid], redQ[tid]);
      }
    }
  } else {
    // fused final: row L2-normalize + @Wr + br -> outp
    __syncthreads();
    float ss8[2][4];
#pragma unroll
    for (int mi = 0; mi < 2; ++mi)
#pragma unroll
      for (int j = 0; j < 4; ++j) ss8[mi][j] = 0.f;
#pragma unroll
    for (int nj = 0; nj < 4; ++nj) {
      int c = wc * 64 + nj * 16 + ni;
      float bcol = bias[c];
#pragma unroll
      for (int mi = 0; mi < 2; ++mi)
#pragma unroll
        for (int j = 0; j < 4; ++j) {
          float v = acc[mi][nj][j] + bcol;
          ss8[mi][j] = fmaf(v, v, ss8[mi][j]);
        }
    }
#pragma unroll
    for (int mk = 1; mk <= 8; mk <<= 1)
#pragma unroll
      for (int mi = 0; mi < 2; ++mi)
#pragma unroll
        for (int j = 0; j < 4; ++j) ss8[mi][j] += __shfl_xor(ss8[mi][j], mk, 64);
    if (ni == 0) {
#pragma unroll
      for (int mi = 0; mi < 2; ++mi)
#pragma unroll
        for (int j = 0; j < 4; ++j)
          atomicAdd(&fss[(wr * 2 + mi) * 16 + l4 + j], ss8[mi][j]);
    }
    __syncthreads();
    if (tid < 64) fss[tid] = 1.f / fmaxf(sqrtf(fss[tid]), 1e-12f);
    __syncthreads();
#pragma unroll
    for (int mi = 0; mi < 2; ++mi)
#pragma unroll
      for (int j = 0; j < 4; ++j) {
        int rl = (wr * 2 + mi) * 16 + l4 + j;
        float inv = fss[rl];
        float o0 = 0.f, o1 = 0.f, o2 = 0.f;
#pragma unroll
        for (int nj = 0; nj < 4; ++nj) {
          int c = wc * 64 + nj * 16 + ni;
          float v = (acc[mi][nj][j] + bias[c]) * inv;
          o0 = fmaf(v, Wr[c * 3 + 0], o0);
          o1 = fmaf(v, Wr[c * 3 + 1], o1);
          o2 = fmaf(v, Wr[c * 3 + 2], o2);
        }
#pragma unroll
        for (int mk = 1; mk <= 8; mk <<= 1) {
          o0 += __shfl_xor(o0, mk, 64);
          o1 += __shfl_xor(o1, mk, 64);
          o2 += __shfl_xor(o2, mk, 64);
        }
        if (ni == 0) {
          atomicAdd(&fob[rl][0], o0);
          atomicAdd(&fob[rl][1], o1);
          atomicAdd(&fob[rl][2], o2);
        }
      }
    __syncthreads();
    if (tid < 64) {
      int row = row0 + tid;
      if (row < nrows) {
        outp[row * 3 + 0] = fob[tid][0] + br[0];
        outp[row * 3 + 1] = fob[tid][1] + br[1];
        outp[row * 3 + 2] = fob[tid][2] + br[2];
      }
    }
  }
}

extern "C" void kernel_launch(void* const* d_in, const int* in_sizes, int n_in,
                              void* d_out, int out_size, void* d_ws, size_t ws_size,
                              hipStream_t stream) {
  const float* x  = (const float*)d_in[0];
  const int*   ei = (const int*)d_in[1];
  const float* W1 = (const float*)d_in[2];
  const float* b1 = (const float*)d_in[3];
  const float* W2 = (const float*)d_in[4];
  const float* b2 = (const float*)d_in[5];
  const float* W3 = (const float*)d_in[6];
  const float* b3 = (const float*)d_in[7];
  const float* W4 = (const float*)d_in[8];
  const float* b4 = (const float*)d_in[9];
  const float* g1 = (const float*)d_in[10];
  const float* be1= (const float*)d_in[11];
  const float* g2 = (const float*)d_in[12];
  const float* be2= (const float*)d_in[13];
  const float* g3 = (const float*)d_in[14];
  const float* be3= (const float*)d_in[15];
  const float* Wr = (const float*)d_in[16];
  const float* br = (const float*)d_in[17];

  const int N = in_sizes[0] / 3;
  const int E = in_sizes[1] / 2;
  const int* src = ei;
  const int* dst = ei + E;
  float* out = (float*)d_out;
  const float invn = 1.0f / (float)N;

  char* wp = (char*)d_ws;
  size_t used = 0;
  auto alloc = [&](size_t bytes) -> void* {
    void* p = (void*)(wp + used);
    used += (bytes + 255) & ~(size_t)255;
    return p;
  };
  u32*   packed = (u32*)alloc((size_t)N * 4);
  int*   rowptr = (int*)alloc((size_t)(N + 1) * 4);
  float* dinv   = (float*)alloc((size_t)N * 4);
  int*   bsums  = (int*)alloc(256 * 4);
  int*   ledge  = (int*)alloc((size_t)E * 4);
  uint2* cw     = (uint2*)alloc((size_t)E * 8);
  float* t1     = (float*)alloc((size_t)N * 3 * 4);
  float* t2     = (float*)alloc((size_t)N * 3 * 4);
  float* t3     = (float*)alloc((size_t)N * 3 * 4);
  __half* phA   = (__half*)alloc((size_t)N * HD * 2);
  __half* phB   = (__half*)alloc((size_t)N * HD * 2);
  __half* phC   = (__half*)alloc((size_t)N * HD * 2);
  __half* phD   = (__half*)alloc((size_t)N * HD * 2);
  float* stats  = (float*)alloc(6 * HD * 4);  // [sum1,sq1,sum2,sq2,sum3,sq3]
  uint4* Whi3   = (uint4*)alloc(3 * 8192 * 16);
  uint4* Wlo3   = (uint4*)alloc(3 * 8192 * 16);
  if (used > ws_size) return;

  float* st1 = stats + 0 * HD;
  float* st2 = stats + 2 * HD;
  float* st3 = stats + 4 * HD;

  const int eb = (E + 255) / 256;
  const int nb = (N + 255) / 256;
  const int pb = (N + 3) / 4;
  const int sb = (N + 1023) / 1024;
  const int gbm = (N + 63) / 64;

  hipMemsetAsync(packed, 0, (size_t)N * 4, stream);
  k_edge_count<<<eb, 256, 0, stream>>>(src, dst, packed, ledge, E);
  k_scan1<<<sb, 1024, 0, stream>>>(packed, rowptr, bsums, stats, N);
  k_scan3<<<sb, 1024, 0, stream>>>(rowptr, bsums, packed, dinv, N, E, sb);
  k_fill<<<eb, 256, 0, stream>>>(src, dst, ledge, rowptr, dinv, cw, E);
  k_wsplit3<<<96, 256, 0, stream>>>(W2, W3, W4, Whi3, Wlo3);

  // ---- layer 1 (fi=3) ----
  k_prop3<<<nb, 256, 0, stream>>>(rowptr, cw, x, nullptr, t1, 1.f, N);
  k_prop3<<<nb, 256, 0, stream>>>(rowptr, cw, t1, x, t2, 2.f, N);
  k_prop3<<<nb, 256, 0, stream>>>(rowptr, cw, t2, t1, t3, 2.f, N);
  k_l1gemm<<<(N + 255) / 256, 128, 0, stream>>>(x, t1, t2, t3, W1, b1, phA,
                                                st1, st1 + HD, 0.01f, N, 256);

  const u64* cw8 = (const u64*)cw;

  // ---- layers 2..4 (raw fp16 H in phA; phi from raw stats at consumers) ----
  auto cheb_layer = [&](const uint4* Whi, const uint4* Wlo, const float* bk,
                        const float* gst, const float* gg, const float* gbe, float phi_slope,
                        float* so, float stat_slope,
                        const float* Wrp, const float* brp, float* outp) {
    k_prop128<1><<<pb, 256, 0, stream>>>(rowptr, cw8, phA, nullptr, phB, 1.f, N, invn,
                                         gst, gg, gbe, nullptr, nullptr, nullptr, phi_slope);
    k_prop128<0><<<pb, 256, 0, stream>>>(rowptr, cw8, phB, phA, phC, 2.f, N, invn,
                                         nullptr, nullptr, nullptr, gst, gg, gbe, phi_slope);
    k_prop128<0><<<pb, 256, 0, stream>>>(rowptr, cw8, phC, phB, phD, 2.f, N, invn,
                                         nullptr, nullptr, nullptr, nullptr, nullptr, nullptr,
                                         0.f);
    k_gemm4m<<<gbm, 256, 0, stream>>>(phA, phB, phC, phD, Whi, Wlo, bk, phA,
                                      so, so ? so + HD : nullptr, stat_slope,
                                      gst, gg, gbe, invn, phi_slope,
                                      Wrp, brp, outp, N);
  };

  cheb_layer(Whi3, Wlo3, b2, st1, g1, be1, 0.01f, st2, 0.01f, nullptr, nullptr, nullptr);
  cheb_layer(Whi3 + 8192, Wlo3 + 8192, b3, st2, g2, be2, 0.01f, st3, 0.0f,
             nullptr, nullptr, nullptr);
  cheb_layer(Whi3 + 16384, Wlo3 + 16384, b4, st3, g3, be3, 0.0f, nullptr, 0.0f, Wr, br, out);
}

// Round 16
// 669.647 us; speedup vs baseline: 1.9826x; 1.1235x over previous
//
#include <hip/hip_runtime.h>
#include <hip/hip_fp16.h>

#define HD 128

typedef __attribute__((ext_vector_type(8))) _Float16 f16x8;
typedef __attribute__((ext_vector_type(4))) float f32x4;
typedef unsigned int u32;

struct h4s { __half2 a, b; };  // 4 fp16 = 8 B

__device__ __forceinline__ float lrelu(float x, float s) { return x > 0.f ? x : s * x; }

// BN scale/shift from raw stats: st[f]=sum, st[HD+f]=sumsq
__device__ __forceinline__ float2 bn_coeff(const float* st, const float* g,
                                           const float* be, float invn, int f) {
  float m = st[f] * invn;
  float v = st[HD + f] * invn - m * m;
  float sc = g[f] * rsqrtf(v + 1e-5f);
  return make_float2(sc, be[f] - m * sc);
}

// ---------------- graph prep ----------------
__global__ void k_edge_count(const int* __restrict__ src, const int* __restrict__ dst,
                             int* __restrict__ degc, int* __restrict__ cnt,
                             int* __restrict__ ledge, int E) {
  int e = blockIdx.x * blockDim.x + threadIdx.x;
  if (e < E) {
    atomicAdd(&degc[src[e]], 1);
    ledge[e] = atomicAdd(&cnt[dst[e]], 1);
  }
}

// + zero the BN stats buffer (block 0)
__global__ __launch_bounds__(1024) void k_scan1(const int* __restrict__ cnt,
                                                int* __restrict__ rowptr,
                                                int* __restrict__ bsums,
                                                float* __restrict__ stats, int n) {
  if (blockIdx.x == 0 && threadIdx.x < 6 * HD) stats[threadIdx.x] = 0.f;
  __shared__ int buf[1024];
  int i = blockIdx.x * 1024 + threadIdx.x;
  int v = (i < n) ? cnt[i] : 0;
  buf[threadIdx.x] = v;
  __syncthreads();
  for (int o = 1; o < 1024; o <<= 1) {
    int t = (threadIdx.x >= (unsigned)o) ? buf[threadIdx.x - o] : 0;
    __syncthreads();
    buf[threadIdx.x] += t;
    __syncthreads();
  }
  if (i < n) rowptr[i] = buf[threadIdx.x] - v;
  if (threadIdx.x == 1023) bsums[blockIdx.x] = buf[1023];
}

__global__ __launch_bounds__(1024) void k_scan3(int* __restrict__ rowptr,
                                                const int* __restrict__ bsums,
                                                const int* __restrict__ degc,
                                                float* __restrict__ dinv, int n, int Etot,
                                                int nb) {
  __shared__ int blockoff;
  if (nb <= 64) {
    if (threadIdx.x < 64) {
      int lane = threadIdx.x;
      int v = (lane < nb) ? bsums[lane] : 0;
      int inc = v;
#pragma unroll
      for (int o = 1; o < 64; o <<= 1) {
        int t = __shfl_up(inc, o, 64);
        if (lane >= o) inc += t;
      }
      if (lane == (int)blockIdx.x) blockoff = inc - v;
    }
  } else if (threadIdx.x == 0) {
    int sum = 0;
    for (int t = 0; t < (int)blockIdx.x; ++t) sum += bsums[t];
    blockoff = sum;
  }
  __syncthreads();
  int i = blockIdx.x * 1024 + threadIdx.x;
  if (i < n) {
    rowptr[i] += blockoff;
    int dg = degc[i];
    dinv[i] = dg > 0 ? rsqrtf((float)dg) : 0.f;
  }
  if (i == 0) rowptr[n] = Etot;
}

// atomic-free CSR fill
__global__ void k_fill(const int* __restrict__ src, const int* __restrict__ dst,
                       const int* __restrict__ ledge, const int* __restrict__ rowptr,
                       const float* __restrict__ dinv, uint2* __restrict__ cw, int E) {
  int e = blockIdx.x * blockDim.x + threadIdx.x;
  if (e < E) {
    int s = src[e], d = dst[e];
    int p = rowptr[d] + ledge[e];
    cw[p] = make_uint2((u32)s, __float_as_uint(-dinv[s] * dinv[d]));
  }
}

// ---------------- props ----------------
__global__ void k_prop3(const int* __restrict__ rowptr, const uint2* __restrict__ cw,
                        const float* __restrict__ Hs, const float* __restrict__ Sub,
                        float* __restrict__ Out, float scale, int n) {
  int r = blockIdx.x * blockDim.x + threadIdx.x;
  if (r >= n) return;
  int b = rowptr[r], e = rowptr[r + 1];
  float a0 = 0.f, a1 = 0.f, a2 = 0.f;
  for (int j = b; j < e; ++j) {
    uint2 m = cw[j];
    int s = (int)m.x;
    float w = __uint_as_float(m.y);
    a0 = fmaf(w, Hs[s * 3 + 0], a0);
    a1 = fmaf(w, Hs[s * 3 + 1], a1);
    a2 = fmaf(w, Hs[s * 3 + 2], a2);
  }
  float r0 = scale * a0, r1 = scale * a1, r2 = scale * a2;
  if (Sub) { r0 -= Sub[r * 3 + 0]; r1 -= Sub[r * 3 + 1]; r2 -= Sub[r * 3 + 2]; }
  Out[r * 3 + 0] = r0; Out[r * 3 + 1] = r1; Out[r * 3 + 2] = r2;
}

// F=128 prop, fp16 feature I/O, fp32 accumulation. One wave per dst row;
// half-wave 8B gathers (2 edges/instr, 4 gathers in flight).
// PHI: deferred phi(v)=sc*lrelu(v,slope)+sh on gathered values, coeffs derived from
// raw BN stats (gst,gg,gbe). Sub-phi likewise via (sst,sg,sbe) when non-null.
template <int PHI>
__global__ __launch_bounds__(256) void k_prop128(
    const int* __restrict__ rowptr, const uint2* __restrict__ cw,
    const __half* __restrict__ Ph, const __half* __restrict__ Sub,
    __half* __restrict__ Outh, float scale, int n, float invn,
    const float* __restrict__ gst, const float* __restrict__ gg, const float* __restrict__ gbe,
    const float* __restrict__ sst, const float* __restrict__ sg, const float* __restrict__ sbe,
    float slope) {
  int r = blockIdx.x * 4 + (int)(threadIdx.x >> 6);
  int lane = threadIdx.x & 63;
  if (r >= n) return;
  int b = rowptr[r], e = rowptr[r + 1];
  int fl = (lane & 31) << 2;
  int half = lane >> 5;
  float ax = 0.f, ay = 0.f, az = 0.f, aw = 0.f, ws = 0.f;
  int j = b;
  for (; j + 7 < e; j += 8) {
    h4s h[4];
    float w[4];
#pragma unroll
    for (int q = 0; q < 4; ++q) {
      int idx = j + 2 * q + half;
      uint2 m = cw[idx];
      w[q] = __uint_as_float(m.y);
      h[q] = *(const h4s*)&Ph[(size_t)m.x * HD + fl];
    }
#pragma unroll
    for (int q = 0; q < 4; ++q) {
      float2 f0 = __half22float2(h[q].a);
      float2 f1 = __half22float2(h[q].b);
      if (PHI) {
        f0.x = lrelu(f0.x, slope); f0.y = lrelu(f0.y, slope);
        f1.x = lrelu(f1.x, slope); f1.y = lrelu(f1.y, slope);
        ws += w[q];
      }
      ax = fmaf(w[q], f0.x, ax);
      ay = fmaf(w[q], f0.y, ay);
      az = fmaf(w[q], f1.x, az);
      aw = fmaf(w[q], f1.y, aw);
    }
  }
  for (; j + 1 < e; j += 2) {
    int idx = j + half;
    uint2 m = cw[idx];
    float w = __uint_as_float(m.y);
    h4s h = *(const h4s*)&Ph[(size_t)m.x * HD + fl];
    float2 f0 = __half22float2(h.a);
    float2 f1 = __half22float2(h.b);
    if (PHI) {
      f0.x = lrelu(f0.x, slope); f0.y = lrelu(f0.y, slope);
      f1.x = lrelu(f1.x, slope); f1.y = lrelu(f1.y, slope);
      ws += w;
    }
    ax = fmaf(w, f0.x, ax);
    ay = fmaf(w, f0.y, ay);
    az = fmaf(w, f1.x, az);
    aw = fmaf(w, f1.y, aw);
  }
  if (j < e && half == 0) {
    uint2 m = cw[j];
    float w = __uint_as_float(m.y);
    h4s h = *(const h4s*)&Ph[(size_t)m.x * HD + fl];
    float2 f0 = __half22float2(h.a);
    float2 f1 = __half22float2(h.b);
    if (PHI) {
      f0.x = lrelu(f0.x, slope); f0.y = lrelu(f0.y, slope);
      f1.x = lrelu(f1.x, slope); f1.y = lrelu(f1.y, slope);
      ws += w;
    }
    ax = fmaf(w, f0.x, ax);
    ay = fmaf(w, f0.y, ay);
    az = fmaf(w, f1.x, az);
    aw = fmaf(w, f1.y, aw);
  }
  ax += __shfl_xor(ax, 32, 64);
  ay += __shfl_xor(ay, 32, 64);
  az += __shfl_xor(az, 32, 64);
  aw += __shfl_xor(aw, 32, 64);
  if (PHI) {
    ws += __shfl_xor(ws, 32, 64);
    float2 c0 = bn_coeff(gst, gg, gbe, invn, fl + 0);
    float2 c1 = bn_coeff(gst, gg, gbe, invn, fl + 1);
    float2 c2 = bn_coeff(gst, gg, gbe, invn, fl + 2);
    float2 c3 = bn_coeff(gst, gg, gbe, invn, fl + 3);
    ax = fmaf(ax, c0.x, ws * c0.y);
    ay = fmaf(ay, c1.x, ws * c1.y);
    az = fmaf(az, c2.x, ws * c2.y);
    aw = fmaf(aw, c3.x, ws * c3.y);
  }
  float4 o = make_float4(scale * ax, scale * ay, scale * az, scale * aw);
  if (Sub) {
    h4s sh4 = *(const h4s*)&Sub[(size_t)r * HD + fl];
    float2 s0 = __half22float2(sh4.a);
    float2 s1 = __half22float2(sh4.b);
    if (sst != nullptr) {
      float2 d0 = bn_coeff(sst, sg, sbe, invn, fl + 0);
      float2 d1 = bn_coeff(sst, sg, sbe, invn, fl + 1);
      float2 d2 = bn_coeff(sst, sg, sbe, invn, fl + 2);
      float2 d3 = bn_coeff(sst, sg, sbe, invn, fl + 3);
      s0.x = fmaf(lrelu(s0.x, slope), d0.x, d0.y);
      s0.y = fmaf(lrelu(s0.y, slope), d1.x, d1.y);
      s1.x = fmaf(lrelu(s1.x, slope), d2.x, d2.y);
      s1.y = fmaf(lrelu(s1.y, slope), d3.x, d3.y);
    }
    o.x -= s0.x; o.y -= s0.y; o.z -= s1.x; o.w -= s1.y;
  }
  if (half == 0) {
    h4s ho;
    ho.a = __float22half2_rn(make_float2(o.x, o.y));
    ho.b = __float22half2_rn(make_float2(o.z, o.w));
    *(h4s*)&Outh[(size_t)r * HD + fl] = ho;
  }
}

// ---------------- layer-1 fused gemm (fi=3, K=4) + fused BN stats, fp16 out ----------------
__global__ __launch_bounds__(128) void k_l1gemm(
    const float* __restrict__ X, const float* __restrict__ T1, const float* __restrict__ T2,
    const float* __restrict__ T3, const float* __restrict__ W1, const float* __restrict__ b1,
    __half* __restrict__ Outh, float* __restrict__ bnsum, float* __restrict__ bnsq,
    float slope, int n, int rpb) {
  int j = threadIdx.x;
  float w[12];
#pragma unroll
  for (int t = 0; t < 4; ++t)
#pragma unroll
    for (int c = 0; c < 3; ++c) w[t * 3 + c] = W1[(t * 3 + c) * HD + j];
  float bj = b1[j];
  int r0 = blockIdx.x * rpb, r1 = min(r0 + rpb, n);
  float s = 0.f, q = 0.f;
  for (int r = r0; r < r1; ++r) {
    float acc = bj;
#pragma unroll
    for (int c = 0; c < 3; ++c) {
      acc = fmaf(X [r * 3 + c], w[0 + c], acc);
      acc = fmaf(T1[r * 3 + c], w[3 + c], acc);
      acc = fmaf(T2[r * 3 + c], w[6 + c], acc);
      acc = fmaf(T3[r * 3 + c], w[9 + c], acc);
    }
    Outh[(size_t)r * HD + j] = __float2half(acc);
    float a = lrelu(acc, slope);
    s += a;
    q = fmaf(a, a, q);
  }
  atomicAdd(&bnsum[j], s);
  atomicAdd(&bnsq[j], q);
}

// ---------------- W pre-split: fp32 -> fp16 hi/lo in MFMA frag-slot order ----------------
__global__ void k_wsplit3(const float* __restrict__ W2, const float* __restrict__ W3,
                          const float* __restrict__ W4, uint4* __restrict__ Whi,
                          uint4* __restrict__ Wlo) {
  int flat = blockIdx.x * 256 + threadIdx.x;  // 0..24575
  int wsel = flat >> 13;
  int f = flat & 8191;
  const float* W = (wsel == 0) ? W2 : (wsel == 1) ? W3 : W4;
  int n = f & 127, K8 = f >> 7;
  int chunk = K8 >> 2, g = K8 & 3;
  f16x8 hv, lv;
#pragma unroll
  for (int i = 0; i < 8; ++i) {
    int k = chunk * 32 + ((i >> 2) << 4) + g * 4 + (i & 3);
    float v = W[(size_t)k * HD + n];
    _Float16 hh = (_Float16)v;
    _Float16 hl = (_Float16)(v - (float)hh);
    hv[i] = hh;
    lv[i] = hl;
  }
  int slot = chunk * 512 + (n >> 4) * 64 + g * 16 + (n & 15);
  Whi[wsel * 8192 + slot] = *(uint4*)&hv;
  Wlo[wsel * 8192 + slot] = *(uint4*)&lv;
}

// ---------------- fused 4-term GEMM via fp16 MFMA (A exact, W 2-term) ----------------
// OUTh = fp16( bias + phi(T0)@W0 + T1@W1 + T2@W2 + T3@W3 ); optional fused BN stats.
// If outp != nullptr: epilogue does row-L2-normalize + @Wr + br -> outp instead.
__global__ __launch_bounds__(256) void k_gemm4m(
    const __half* __restrict__ T0, const __half* __restrict__ T1,
    const __half* __restrict__ T2, const __half* __restrict__ T3,
    const uint4* __restrict__ Whi, const uint4* __restrict__ Wlo,
    const float* __restrict__ bias, __half* __restrict__ OUTh,
    float* bnsum, float* bnsq, float stat_slope,
    const float* __restrict__ gst, const float* __restrict__ gg,
    const float* __restrict__ gbe, float invn, float phi_slope,
    const float* __restrict__ Wr, const float* __restrict__ br, float* __restrict__ outp,
    int nrows) {
  __shared__ __half sA[2048];              // 256 slots x 8 fp16
  __shared__ __half sWh[4096], sWl[4096];  // 512 slots x 8 fp16 each
  __shared__ float redS[128], redQ[128];
  __shared__ float fss[64];
  __shared__ float fob[64][3];

  int tid = threadIdx.x;
  int lane = tid & 63, w = tid >> 6, wr = w >> 1, wc = w & 1;
  int g = (tid >> 4) & 3;
  int ri = tid & 15;
  int row0 = blockIdx.x * 64;
  int arow = row0 + w * 16 + ri;
  bool aval = arow < nrows;

  f32x4 zero = {0.f, 0.f, 0.f, 0.f};
  f32x4 acc[2][4];
#pragma unroll
  for (int mi = 0; mi < 2; ++mi)
#pragma unroll
    for (int nj = 0; nj < 4; ++nj) acc[mi][nj] = zero;

  if (tid < 128) { redS[tid] = 0.f; redQ[tid] = 0.f; }
  if (tid < 64) { fss[tid] = 0.f; fob[tid][0] = 0.f; fob[tid][1] = 0.f; fob[tid][2] = 0.f; }

  for (int chunk = 0; chunk < 16; ++chunk) {
    const __half* Ts = (chunk < 4) ? T0 : (chunk < 8) ? T1 : (chunk < 12) ? T2 : T3;
    int kc = chunk & 3;
    h4s va, vb;
    *(uint2*)&va = make_uint2(0u, 0u);
    *(uint2*)&vb = make_uint2(0u, 0u);
    if (aval) {
      const __half* ap = Ts + (size_t)arow * HD + kc * 32 + g * 4;
      va = *(const h4s*)ap;
      vb = *(const h4s*)(ap + 16);
    }
    size_t wbase = (size_t)chunk * 512;
    uint4 wh0 = Whi[wbase + tid], wh1 = Whi[wbase + 256 + tid];
    uint4 wl0 = Wlo[wbase + tid], wl1 = Wlo[wbase + 256 + tid];

    __syncthreads();

    if (gst != nullptr && chunk < 4) {
      float fv[8];
      float2 f0 = __half22float2(va.a), f1 = __half22float2(va.b);
      float2 f2 = __half22float2(vb.a), f3 = __half22float2(vb.b);
      fv[0] = f0.x; fv[1] = f0.y; fv[2] = f1.x; fv[3] = f1.y;
      fv[4] = f2.x; fv[5] = f2.y; fv[6] = f3.x; fv[7] = f3.y;
#pragma unroll
      for (int i = 0; i < 8; ++i) {
        int f = kc * 32 + g * 4 + (i & 3) + ((i >> 2) << 4);
        float2 cs = bn_coeff(gst, gg, gbe, invn, f);
        fv[i] = fmaf(lrelu(fv[i], phi_slope), cs.x, cs.y);
      }
      va.a = __float22half2_rn(make_float2(fv[0], fv[1]));
      va.b = __float22half2_rn(make_float2(fv[2], fv[3]));
      vb.a = __float22half2_rn(make_float2(fv[4], fv[5]));
      vb.b = __float22half2_rn(make_float2(fv[6], fv[7]));
    }
    *(h4s*)&sA[tid * 8] = va;
    *(h4s*)&sA[tid * 8 + 4] = vb;
    *(uint4*)&sWh[tid * 8] = wh0;
    *(uint4*)&sWh[(256 + tid) * 8] = wh1;
    *(uint4*)&sWl[tid * 8] = wl0;
    *(uint4*)&sWl[(256 + tid) * 8] = wl1;
    __syncthreads();

    f16x8 a[2], bh[4], bl[4];
#pragma unroll
    for (int mi = 0; mi < 2; ++mi)
      a[mi] = *(const f16x8*)&sA[((wr * 2 + mi) * 64 + lane) * 8];
#pragma unroll
    for (int nj = 0; nj < 4; ++nj) {
      bh[nj] = *(const f16x8*)&sWh[((wc * 4 + nj) * 64 + lane) * 8];
      bl[nj] = *(const f16x8*)&sWl[((wc * 4 + nj) * 64 + lane) * 8];
    }
#pragma unroll
    for (int mi = 0; mi < 2; ++mi)
#pragma unroll
      for (int nj = 0; nj < 4; ++nj) {
        acc[mi][nj] = __builtin_amdgcn_mfma_f32_16x16x32_f16(a[mi], bh[nj], acc[mi][nj], 0, 0, 0);
        acc[mi][nj] = __builtin_amdgcn_mfma_f32_16x16x32_f16(a[mi], bl[nj], acc[mi][nj], 0, 0, 0);
      }
  }

  int l4 = (lane >> 4) * 4, ni = lane & 15;

  if (outp == nullptr) {
    bool stats = (bnsum != nullptr);
#pragma unroll
    for (int nj = 0; nj < 4; ++nj) {
      int c = wc * 64 + nj * 16 + ni;
      float bcol = bias[c];
      float s = 0.f, q = 0.f;
#pragma unroll
      for (int mi = 0; mi < 2; ++mi)
#pragma unroll
        for (int j = 0; j < 4; ++j) {
          int row = row0 + (wr * 2 + mi) * 16 + l4 + j;
          if (row < nrows) {
            float v = acc[mi][nj][j] + bcol;
            OUTh[(size_t)row * HD + c] = __float2half(v);
            if (stats) {
              float a = lrelu(v, stat_slope);
              s += a;
              q = fmaf(a, a, q);
            }
          }
        }
      if (stats) {
        s += __shfl_xor(s, 16, 64);
        s += __shfl_xor(s, 32, 64);
        q += __shfl_xor(q, 16, 64);
        q += __shfl_xor(q, 32, 64);
        if (lane < 16) {
          atomicAdd(&redS[c], s);
          atomicAdd(&redQ[c], q);
        }
      }
    }
    if (stats) {
      __syncthreads();
      if (tid < 128) {
        atomicAdd(&bnsum[tid], redS[tid]);
        atomicAdd(&bnsq[tid], redQ[tid]);
      }
    }
  } else {
    // fused final: row L2-normalize + @Wr + br -> outp
    __syncthreads();
    float ss8[2][4];
#pragma unroll
    for (int mi = 0; mi < 2; ++mi)
#pragma unroll
      for (int j = 0; j < 4; ++j) ss8[mi][j] = 0.f;
#pragma unroll
    for (int nj = 0; nj < 4; ++nj) {
      int c = wc * 64 + nj * 16 + ni;
      float bcol = bias[c];
#pragma unroll
      for (int mi = 0; mi < 2; ++mi)
#pragma unroll
        for (int j = 0; j < 4; ++j) {
          float v = acc[mi][nj][j] + bcol;
          ss8[mi][j] = fmaf(v, v, ss8[mi][j]);
        }
    }
#pragma unroll
    for (int mk = 1; mk <= 8; mk <<= 1)
#pragma unroll
      for (int mi = 0; mi < 2; ++mi)
#pragma unroll
        for (int j = 0; j < 4; ++j) ss8[mi][j] += __shfl_xor(ss8[mi][j], mk, 64);
    if (ni == 0) {
#pragma unroll
      for (int mi = 0; mi < 2; ++mi)
#pragma unroll
        for (int j = 0; j < 4; ++j)
          atomicAdd(&fss[(wr * 2 + mi) * 16 + l4 + j], ss8[mi][j]);
    }
    __syncthreads();
    if (tid < 64) fss[tid] = 1.f / fmaxf(sqrtf(fss[tid]), 1e-12f);
    __syncthreads();
#pragma unroll
    for (int mi = 0; mi < 2; ++mi)
#pragma unroll
      for (int j = 0; j < 4; ++j) {
        int rl = (wr * 2 + mi) * 16 + l4 + j;
        float inv = fss[rl];
        float o0 = 0.f, o1 = 0.f, o2 = 0.f;
#pragma unroll
        for (int nj = 0; nj < 4; ++nj) {
          int c = wc * 64 + nj * 16 + ni;
          float v = (acc[mi][nj][j] + bias[c]) * inv;
          o0 = fmaf(v, Wr[c * 3 + 0], o0);
          o1 = fmaf(v, Wr[c * 3 + 1], o1);
          o2 = fmaf(v, Wr[c * 3 + 2], o2);
        }
#pragma unroll
        for (int mk = 1; mk <= 8; mk <<= 1) {
          o0 += __shfl_xor(o0, mk, 64);
          o1 += __shfl_xor(o1, mk, 64);
          o2 += __shfl_xor(o2, mk, 64);
        }
        if (ni == 0) {
          atomicAdd(&fob[rl][0], o0);
          atomicAdd(&fob[rl][1], o1);
          atomicAdd(&fob[rl][2], o2);
        }
      }
    __syncthreads();
    if (tid < 64) {
      int row = row0 + tid;
      if (row < nrows) {
        outp[row * 3 + 0] = fob[tid][0] + br[0];
        outp[row * 3 + 1] = fob[tid][1] + br[1];
        outp[row * 3 + 2] = fob[tid][2] + br[2];
      }
    }
  }
}

extern "C" void kernel_launch(void* const* d_in, const int* in_sizes, int n_in,
                              void* d_out, int out_size, void* d_ws, size_t ws_size,
                              hipStream_t stream) {
  const float* x  = (const float*)d_in[0];
  const int*   ei = (const int*)d_in[1];
  const float* W1 = (const float*)d_in[2];
  const float* b1 = (const float*)d_in[3];
  const float* W2 = (const float*)d_in[4];
  const float* b2 = (const float*)d_in[5];
  const float* W3 = (const float*)d_in[6];
  const float* b3 = (const float*)d_in[7];
  const float* W4 = (const float*)d_in[8];
  const float* b4 = (const float*)d_in[9];
  const float* g1 = (const float*)d_in[10];
  const float* be1= (const float*)d_in[11];
  const float* g2 = (const float*)d_in[12];
  const float* be2= (const float*)d_in[13];
  const float* g3 = (const float*)d_in[14];
  const float* be3= (const float*)d_in[15];
  const float* Wr = (const float*)d_in[16];
  const float* br = (const float*)d_in[17];

  const int N = in_sizes[0] / 3;
  const int E = in_sizes[1] / 2;
  const int* src = ei;
  const int* dst = ei + E;
  float* out = (float*)d_out;
  const float invn = 1.0f / (float)N;

  char* wp = (char*)d_ws;
  size_t used = 0;
  auto alloc = [&](size_t bytes) -> void* {
    void* p = (void*)(wp + used);
    used += (bytes + 255) & ~(size_t)255;
    return p;
  };
  int*   deg2   = (int*)alloc((size_t)2 * N * 4);
  int*   rowptr = (int*)alloc((size_t)(N + 1) * 4);
  float* dinv   = (float*)alloc((size_t)N * 4);
  int*   bsums  = (int*)alloc(256 * 4);
  int*   ledge  = (int*)alloc((size_t)E * 4);
  uint2* cw     = (uint2*)alloc((size_t)E * 8);
  float* t1     = (float*)alloc((size_t)N * 3 * 4);
  float* t2     = (float*)alloc((size_t)N * 3 * 4);
  float* t3     = (float*)alloc((size_t)N * 3 * 4);
  __half* phA   = (__half*)alloc((size_t)N * HD * 2);
  __half* phB   = (__half*)alloc((size_t)N * HD * 2);
  __half* phC   = (__half*)alloc((size_t)N * HD * 2);
  __half* phD   = (__half*)alloc((size_t)N * HD * 2);
  float* stats  = (float*)alloc(6 * HD * 4);  // [sum1,sq1,sum2,sq2,sum3,sq3]
  uint4* Whi3   = (uint4*)alloc(3 * 8192 * 16);
  uint4* Wlo3   = (uint4*)alloc(3 * 8192 * 16);
  if (used > ws_size) return;

  int* degc = deg2;
  int* cnt  = deg2 + N;
  float* st1 = stats + 0 * HD;
  float* st2 = stats + 2 * HD;
  float* st3 = stats + 4 * HD;

  const int eb = (E + 255) / 256;
  const int nb = (N + 255) / 256;
  const int pb = (N + 3) / 4;
  const int sb = (N + 1023) / 1024;
  const int gbm = (N + 63) / 64;

  hipMemsetAsync(deg2, 0, (size_t)2 * N * 4, stream);
  k_edge_count<<<eb, 256, 0, stream>>>(src, dst, degc, cnt, ledge, E);
  k_scan1<<<sb, 1024, 0, stream>>>(cnt, rowptr, bsums, stats, N);
  k_scan3<<<sb, 1024, 0, stream>>>(rowptr, bsums, degc, dinv, N, E, sb);
  k_fill<<<eb, 256, 0, stream>>>(src, dst, ledge, rowptr, dinv, cw, E);
  k_wsplit3<<<96, 256, 0, stream>>>(W2, W3, W4, Whi3, Wlo3);

  // ---- layer 1 (fi=3) ----
  k_prop3<<<nb, 256, 0, stream>>>(rowptr, cw, x, nullptr, t1, 1.f, N);
  k_prop3<<<nb, 256, 0, stream>>>(rowptr, cw, t1, x, t2, 2.f, N);
  k_prop3<<<nb, 256, 0, stream>>>(rowptr, cw, t2, t1, t3, 2.f, N);
  k_l1gemm<<<(N + 255) / 256, 128, 0, stream>>>(x, t1, t2, t3, W1, b1, phA,
                                                st1, st1 + HD, 0.01f, N, 256);

  // ---- layers 2..4 (raw fp16 H in phA; phi from raw stats at consumers) ----
  auto cheb_layer = [&](const uint4* Whi, const uint4* Wlo, const float* bk,
                        const float* gst, const float* gg, const float* gbe, float phi_slope,
                        float* so, float stat_slope,
                        const float* Wrp, const float* brp, float* outp) {
    k_prop128<1><<<pb, 256, 0, stream>>>(rowptr, cw, phA, nullptr, phB, 1.f, N, invn,
                                         gst, gg, gbe, nullptr, nullptr, nullptr, phi_slope);
    k_prop128<0><<<pb, 256, 0, stream>>>(rowptr, cw, phB, phA, phC, 2.f, N, invn,
                                         nullptr, nullptr, nullptr, gst, gg, gbe, phi_slope);
    k_prop128<0><<<pb, 256, 0, stream>>>(rowptr, cw, phC, phB, phD, 2.f, N, invn,
                                         nullptr, nullptr, nullptr, nullptr, nullptr, nullptr,
                                         0.f);
    k_gemm4m<<<gbm, 256, 0, stream>>>(phA, phB, phC, phD, Whi, Wlo, bk, phA,
                                      so, so ? so + HD : nullptr, stat_slope,
                                      gst, gg, gbe, invn, phi_slope,
                                      Wrp, brp, outp, N);
  };

  cheb_layer(Whi3, Wlo3, b2, st1, g1, be1, 0.01f, st2, 0.01f, nullptr, nullptr, nullptr);
  cheb_layer(Whi3 + 8192, Wlo3 + 8192, b3, st2, g2, be2, 0.01f, st3, 0.0f,
             nullptr, nullptr, nullptr);
  cheb_layer(Whi3 + 16384, Wlo3 + 16384, b4, st3, g3, be3, 0.0f, nullptr, 0.0f, Wr, br, out);
}